// Round 14
// baseline (52.915 us; speedup 1.0000x reference)
//
#include <hip/hip_runtime.h>

#define HW 262144            // 512*512
#define TSIZE 524288         // 2^19 entries per level
#define HMASK 524287u
#define PRIME2 2654435761u

#define NSTG 10              // levels 0..9 staged in LDS (n <= 42)
#define STG_TOT 6365         // sum of (NS[l]+2)^2 for l<10 (float2) = 50,920 B
#define QUAD_TOT 48703       // sum of (NS[l]+2)^2 for l=10..15 (32B quads)
#define QUAD_F4_OFF 3184     // 50,920 B padded to 50,944 B -> /16
#define WS_NEED 1609440      // 50,944 + 48,703*32
#define BLK 512

__device__ __constant__ int c_NS10[10]  = {8, 9, 11, 13, 16, 20, 24, 29, 35, 42};
__device__ __constant__ int c_OFF10[11] = {0, 100, 221, 390, 615, 939, 1423, 2099,
                                           3060, 4429, 6365};
__device__ __constant__ int c_WQ[6]   = {52, 63, 75, 90, 108, 129};
__device__ __constant__ int c_QOFF[7] = {0, 2704, 6673, 12298, 20398, 32062, 48703};

// Reference semantics (locked R1-R7): JAX/XLA f32:
//   hx = int32(fl32(cx*n)); bx = floorf(fl32(cx*rcp)), rcp = fl32(1/fl32(1/n));
//   NS[15] = 127.
// Ladder: R7 93 -> R8 70 -> R9 67 -> R10 57.7 -> R11 47.9 -> R12 65.6 (bad order)
// -> R13 51.4 (dense staging + dup: ~0 effect on main kernel => NOT
// probe-throughput-bound; counters say latency-bound at 16 waves/CU).
// R14: occupancy attack. 50.9KB LDS (levels 0..9) -> 3 blocks/CU = 24 waves;
// levels 10..15 via 32B QUAD cells (all 4 corners in ONE cache line).

// ---- phase 1: build dense scratch: staged grids (f2) + quad grids (2xf4) ----
__global__ __launch_bounds__(256)
void dehash_kernel(const float* __restrict__ table, float2* __restrict__ ws2)
{
    const int e = blockIdx.x * 256 + threadIdx.x;
    const float2* __restrict__ tab2 = reinterpret_cast<const float2*>(table);

    if (e < STG_TOT) {
        int l = 0;
        #pragma unroll
        for (int i = 1; i < NSTG; ++i) l += (e >= c_OFF10[i]);
        const int W   = c_NS10[l] + 2;
        const int rel = e - c_OFF10[l];
        const int j   = rel / W;
        const int i2  = rel - j * W;
        const unsigned idx = ((unsigned)i2 ^ ((unsigned)j * PRIME2)) & HMASK;
        ws2[e] = tab2[(size_t)l * TSIZE + idx];
    } else if (e < STG_TOT + QUAD_TOT) {
        const int eq = e - STG_TOT;
        int k = 0;
        #pragma unroll
        for (int i = 1; i < 6; ++i) k += (eq >= c_QOFF[i]);
        const int W   = c_WQ[k];
        const int rel = eq - c_QOFF[k];
        const int j   = rel / W;
        const int i2  = rel - j * W;
        const float2* __restrict__ tabl = tab2 + (size_t)(10 + k) * TSIZE;
        const unsigned jp0 = (unsigned)j * PRIME2;
        const unsigned jp1 = (unsigned)(j + 1) * PRIME2;
        const float2 f00 = tabl[((unsigned)i2       ^ jp0) & HMASK];
        const float2 f10 = tabl[((unsigned)(i2 + 1) ^ jp0) & HMASK];
        const float2 f01 = tabl[((unsigned)i2       ^ jp1) & HMASK];
        const float2 f11 = tabl[((unsigned)(i2 + 1) ^ jp1) & HMASK];
        float4* __restrict__ quad = reinterpret_cast<float4*>(ws2) + QUAD_F4_OFF;
        quad[2 * eq]     = make_float4(f00.x, f00.y, f10.x, f10.y);
        quad[2 * eq + 1] = make_float4(f01.x, f01.y, f11.x, f11.y);
    }
}

// ---- phase 2: fused encode, 24 waves/CU ----
__global__ __launch_bounds__(BLK, 6)
void hashenc_fused(const float* __restrict__ coord,
                   const float2* __restrict__ ws2,
                   float* __restrict__ out)
{
    constexpr int NS[10]  = {8, 9, 11, 13, 16, 20, 24, 29, 35, 42};
    constexpr int OFF[10] = {0, 100, 221, 390, 615, 939, 1423, 2099, 3060, 4429};
    constexpr int NSD[6]  = {50, 61, 73, 88, 106, 127};
    constexpr int WQ[6]   = {52, 63, 75, 90, 108, 129};
    constexpr int QOFF[6] = {0, 2704, 6673, 12298, 20398, 32062};

    __shared__ float2 smem[STG_TOT];   // 50,920 B -> 3 blocks/CU

    // ---- stage levels 0..9 from dense scratch (coalesced) ----
    for (int e = threadIdx.x; e < STG_TOT; e += BLK)
        smem[e] = ws2[e];

    const int g   = blockIdx.x * BLK + threadIdx.x;   // 0..1048575 (1 px/thread)
    const int b   = g >> 18;                          // batch (HW = 2^18)
    const int pos = g & (HW - 1);

    const float* cbase = coord + (size_t)b * (2 * HW);
    const float cx = cbase[pos];
    const float cy = cbase[HW + pos];

    float* outb = out + (size_t)b * (32 * HW) + pos;

    __syncthreads();

    // ---- issue all 12 quad gathers NOW: one 64B line per pixel-level,
    //      latency hidden under the LDS compute below ----
    float4 q0[6], q1[6];
    const float4* __restrict__ quad =
        reinterpret_cast<const float4*>(ws2) + QUAD_F4_OFF;
    #pragma unroll
    for (int k = 0; k < 6; ++k) {
        const float n = (float)NSD[k];
        const int hx = (int)(cx * n);
        const int hy = (int)(cy * n);
        const int base = QOFF[k] + hy * WQ[k] + hx;
        q0[k] = quad[2 * base];       // f00 | f10
        q1[k] = quad[2 * base + 1];   // f01 | f11
    }

    // ---- staged levels 0..9 from LDS ----
    #pragma unroll
    for (int l = 0; l < NSTG; ++l) {
        const float n   = (float)NS[l];
        const float inv = 1.0f / n;
        const float rcp = 1.0f / inv;
        const int   W   = NS[l] + 2;
        const float2* __restrict__ sl = smem + OFF[l];

        const int hx = (int)(cx * n);
        const int hy = (int)(cy * n);
        const float bx = floorf(cx * rcp);
        const float by = floorf(cy * rcp);

        const int base = hy * W + hx;
        const float2 f00 = sl[base];
        const float2 f10 = sl[base + 1];
        const float2 f01 = sl[base + W];
        const float2 f11 = sl[base + W + 1];

        const float wx_lo = ((bx + 1.0f) * inv - cx) * n;
        const float wx_hi = (cx - bx * inv) * n;
        const float wy_lo = ((by + 1.0f) * inv - cy) * n;
        const float wy_hi = (cy - by * inv) * n;

        const float r1x = f00.x * wx_lo + f10.x * wx_hi;
        const float r1y = f00.y * wx_lo + f10.y * wx_hi;
        const float r2x = f01.x * wx_lo + f11.x * wx_hi;
        const float r2y = f01.y * wx_lo + f11.y * wx_hi;

        __builtin_nontemporal_store(r1x * wy_lo + r2x * wy_hi,
                                    outb + (size_t)(2 * l)     * HW);
        __builtin_nontemporal_store(r1y * wy_lo + r2y * wy_hi,
                                    outb + (size_t)(2 * l + 1) * HW);
    }

    // ---- direct levels 10..15: blend the landed quads ----
    #pragma unroll
    for (int k = 0; k < 6; ++k) {
        const int   l   = 10 + k;
        const float n   = (float)NSD[k];
        const float inv = 1.0f / n;
        const float rcp = 1.0f / inv;

        const float bx = floorf(cx * rcp);
        const float by = floorf(cy * rcp);

        const float wx_lo = ((bx + 1.0f) * inv - cx) * n;
        const float wx_hi = (cx - bx * inv) * n;
        const float wy_lo = ((by + 1.0f) * inv - cy) * n;
        const float wy_hi = (cy - by * inv) * n;

        const float r1x = q0[k].x * wx_lo + q0[k].z * wx_hi;
        const float r1y = q0[k].y * wx_lo + q0[k].w * wx_hi;
        const float r2x = q1[k].x * wx_lo + q1[k].z * wx_hi;
        const float r2y = q1[k].y * wx_lo + q1[k].w * wx_hi;

        __builtin_nontemporal_store(r1x * wy_lo + r2x * wy_hi,
                                    outb + (size_t)(2 * l)     * HW);
        __builtin_nontemporal_store(r1y * wy_lo + r2y * wy_hi,
                                    outb + (size_t)(2 * l + 1) * HW);
    }
}

// ---- fallback (ws too small): R11 structure, proven 47.9us ----
__global__ __launch_bounds__(1024)
void hashenc_r11(const float* __restrict__ coord,
                 const float* __restrict__ table,
                 float* __restrict__ out)
{
    constexpr int NS[13]  = {8, 9, 11, 13, 16, 20, 24, 29, 35, 42, 50, 61, 73};
    constexpr int OFF[13] = {0, 100, 221, 390, 615, 939, 1423, 2099, 3060, 4429,
                             6365, 9069, 13038};
    constexpr int NSD[3]  = {88, 106, 127};

    extern __shared__ float2 smemd[];
    const float2* __restrict__ tab2 = reinterpret_cast<const float2*>(table);

    #pragma unroll
    for (int l = 0; l < 13; ++l) {
        const int W  = NS[l] + 2;
        const int SZ = W * W;
        const float2* __restrict__ tabl = tab2 + (size_t)l * TSIZE;
        for (int e = threadIdx.x; e < SZ; e += 1024) {
            const int j = e / W;
            const int i = e - j * W;
            smemd[OFF[l] + e] = tabl[((unsigned)i ^ ((unsigned)j * PRIME2)) & HMASK];
        }
    }

    const int g   = blockIdx.x * 1024 + threadIdx.x;
    const int P   = g << 1;
    const int b   = P >> 18;
    const int pos = P & (HW - 1);
    const float* cbase = coord + (size_t)b * (2 * HW);
    const float2 cxp = *reinterpret_cast<const float2*>(cbase + pos);
    const float2 cyp = *reinterpret_cast<const float2*>(cbase + HW + pos);
    const float cxa[2] = {cxp.x, cxp.y};
    const float cya[2] = {cyp.x, cyp.y};
    float* outb = out + (size_t)b * (32 * HW) + pos;

    __syncthreads();

    float2 gd[3][8];
    #pragma unroll
    for (int k = 0; k < 3; ++k) {
        const float n = (float)NSD[k];
        const float2* __restrict__ tabl = tab2 + (size_t)(13 + k) * TSIZE;
        #pragma unroll
        for (int p = 0; p < 2; ++p) {
            const int hx = (int)(cxa[p] * n);
            const int hy = (int)(cya[p] * n);
            const unsigned hyp0 = (unsigned)hy * PRIME2;
            const unsigned hyp1 = (unsigned)(hy + 1) * PRIME2;
            gd[k][p * 4 + 0] = tabl[((unsigned)hx       ^ hyp0) & HMASK];
            gd[k][p * 4 + 1] = tabl[((unsigned)(hx + 1) ^ hyp0) & HMASK];
            gd[k][p * 4 + 2] = tabl[((unsigned)hx       ^ hyp1) & HMASK];
            gd[k][p * 4 + 3] = tabl[((unsigned)(hx + 1) ^ hyp1) & HMASK];
        }
    }

    #pragma unroll
    for (int l = 0; l < 13; ++l) {
        const float n   = (float)NS[l];
        const float inv = 1.0f / n;
        const float rcp = 1.0f / inv;
        const int   W   = NS[l] + 2;
        const float2* __restrict__ sl = smemd + OFF[l];
        float o0[2], o1[2];
        #pragma unroll
        for (int p = 0; p < 2; ++p) {
            const float cx = cxa[p], cy = cya[p];
            const int hx = (int)(cx * n);
            const int hy = (int)(cy * n);
            const float bx = floorf(cx * rcp);
            const float by = floorf(cy * rcp);
            const int base = hy * W + hx;
            const float2 f00 = sl[base], f10 = sl[base + 1];
            const float2 f01 = sl[base + W], f11 = sl[base + W + 1];
            const float wx_lo = ((bx + 1.0f) * inv - cx) * n;
            const float wx_hi = (cx - bx * inv) * n;
            const float wy_lo = ((by + 1.0f) * inv - cy) * n;
            const float wy_hi = (cy - by * inv) * n;
            const float r1x = f00.x * wx_lo + f10.x * wx_hi;
            const float r1y = f00.y * wx_lo + f10.y * wx_hi;
            const float r2x = f01.x * wx_lo + f11.x * wx_hi;
            const float r2y = f01.y * wx_lo + f11.y * wx_hi;
            o0[p] = r1x * wy_lo + r2x * wy_hi;
            o1[p] = r1y * wy_lo + r2y * wy_hi;
        }
        *reinterpret_cast<float2*>(outb + (size_t)(2 * l)     * HW) = make_float2(o0[0], o0[1]);
        *reinterpret_cast<float2*>(outb + (size_t)(2 * l + 1) * HW) = make_float2(o1[0], o1[1]);
    }

    #pragma unroll
    for (int k = 0; k < 3; ++k) {
        const int   l   = 13 + k;
        const float n   = (float)NSD[k];
        const float inv = 1.0f / n;
        const float rcp = 1.0f / inv;
        float o0[2], o1[2];
        #pragma unroll
        for (int p = 0; p < 2; ++p) {
            const float cx = cxa[p], cy = cya[p];
            const float bx = floorf(cx * rcp);
            const float by = floorf(cy * rcp);
            const float2 f00 = gd[k][p * 4 + 0], f10 = gd[k][p * 4 + 1];
            const float2 f01 = gd[k][p * 4 + 2], f11 = gd[k][p * 4 + 3];
            const float wx_lo = ((bx + 1.0f) * inv - cx) * n;
            const float wx_hi = (cx - bx * inv) * n;
            const float wy_lo = ((by + 1.0f) * inv - cy) * n;
            const float wy_hi = (cy - by * inv) * n;
            const float r1x = f00.x * wx_lo + f10.x * wx_hi;
            const float r1y = f00.y * wx_lo + f10.y * wx_hi;
            const float r2x = f01.x * wx_lo + f11.x * wx_hi;
            const float r2y = f01.y * wx_lo + f11.y * wx_hi;
            o0[p] = r1x * wy_lo + r2x * wy_hi;
            o1[p] = r1y * wy_lo + r2y * wy_hi;
        }
        *reinterpret_cast<float2*>(outb + (size_t)(2 * l)     * HW) = make_float2(o0[0], o0[1]);
        *reinterpret_cast<float2*>(outb + (size_t)(2 * l + 1) * HW) = make_float2(o1[0], o1[1]);
    }
}

extern "C" void kernel_launch(void* const* d_in, const int* in_sizes, int n_in,
                              void* d_out, int out_size, void* d_ws, size_t ws_size,
                              hipStream_t stream) {
    const float* coord = (const float*)d_in[0];
    const float* table = (const float*)d_in[1];
    if (n_in >= 2 && in_sizes[0] > in_sizes[1]) {   // size-based disambiguation
        coord = (const float*)d_in[1];
        table = (const float*)d_in[0];
    }
    float* out = (float*)d_out;

    if (ws_size >= (size_t)WS_NEED && d_ws != nullptr) {
        float2* ws2 = (float2*)d_ws;
        // phase 1: 6365 staged + 48703 quad entries = 55068 -> 216 blocks
        dehash_kernel<<<(STG_TOT + QUAD_TOT + 255) / 256, 256, 0, stream>>>(table, ws2);
        // phase 2: 1M px / (512 thr * 1 px) = 2048 blocks, 50.9KB LDS, 3 blk/CU
        hashenc_fused<<<2048, BLK, 0, stream>>>(coord, ws2, out);
    } else {
        const int lds_bytes = 18663 * (int)sizeof(float2);
        (void)hipFuncSetAttribute((const void*)hashenc_r11,
                                  hipFuncAttributeMaxDynamicSharedMemorySize,
                                  lds_bytes);
        hashenc_r11<<<512, 1024, lds_bytes, stream>>>(coord, table, out);
    }
}